// Round 1
// baseline (1129.880 us; speedup 1.0000x reference)
//
#include <hip/hip_runtime.h>
#include <math.h>

#define DEVI __device__ __forceinline__

constexpr int CAMS = 6;
constexpr int CH   = 256;
constexpr int LTOT = 12096;   // 9216 + 2304 + 576
constexpr int TPC  = 189;     // 64-row tiles per camera
constexpr int LIMG = 11520;   // 9216 + 2304

// ---------------- workspace layout (float units) ----------------
constexpr size_t WS_OM = 0;                               // out_mem [6][12096][256]
constexpr size_t WS_SC = WS_OM + (size_t)CAMS*LTOT*CH;    // scores  [6][12096]
constexpr size_t WS_TI = WS_SC + (size_t)CAMS*LTOT;       // topk_ind  600 (int32)
constexpr size_t WS_TS = WS_TI + 768;                     // topk_scores 600
constexpr size_t WS_DA = WS_TS + 768;                     // dyn_all [600][64][4]
constexpr size_t WS_GI = WS_DA + (size_t)600*256;         // gidx 200 (int32)
constexpr size_t WS_GS = WS_GI + 256;                     // gvals 200 (unused downstream)
constexpr size_t WS_GA = WS_GS + 256;                     // gamma [6][256]
constexpr size_t WS_BE = WS_GA + 1536;                    // beta  [6][256]

// ---------------- output layout (float units) ----------------
constexpr size_t O_FF  = 0;                               // feat_flatten [6][11520][256]
constexpr size_t O_SP  = (size_t)CAMS*LIMG*CH;            // spatial [2][2]
constexpr size_t O_L2I = O_SP + 4;                        // lidar2img [1][6][4][4]
constexpr size_t O_DQ  = O_L2I + 96;                      // dyn_query [1][200][64][4]
constexpr size_t O_QF  = O_DQ + (size_t)200*64*4;         // qf_out [1][200][256]

DEVI float anchor_comp(int l, int j) {
    int W, wsh, ll; float Wf, Hf;
    if (l < 9216)      { W=128; wsh=7; Wf=128.f; Hf=72.f; ll=l; }
    else if (l < 11520){ W=64;  wsh=6; Wf=64.f;  Hf=36.f; ll=l-9216; }
    else               { W=32;  wsh=5; Wf=32.f;  Hf=18.f; ll=l-11520; }
    int y = ll >> wsh, x = ll & (W-1);
    float px = (x + 0.5f) / Wf;
    float py = (y + 0.5f) / Hf;
    bool valid = (px > 0.01f) && (px < 0.99f) && (py > 0.01f) && (py < 0.99f);
    if (!valid) return INFINITY;
    float p = (j == 0) ? px : py;
    return logf(p / (1.f - p));
}

// =====================================================================
// K1: fused  proj -> mask -> enc -> LayerNorm -> (out_mem, scores)
// block = 256 threads, 64 token rows x 256 channels
// =====================================================================
__global__ __launch_bounds__(256, 2)
void k_encoder(const float* __restrict__ f0, const float* __restrict__ f1, const float* __restrict__ f2,
               const float* __restrict__ wp0, const float* __restrict__ wp1, const float* __restrict__ wp2,
               const float* __restrict__ w_enc, const float* __restrict__ b_enc,
               const float* __restrict__ ln_g, const float* __restrict__ ln_b,
               const float* __restrict__ w_cls, const float* __restrict__ b_cls,
               float* __restrict__ out_mem, float* __restrict__ scores)
{
    __shared__ __align__(16) float lds[64*256];   // 64 KB, dual-use
    const int bx = blockIdx.x;
    const int n  = bx / TPC;
    const int l0 = (bx % TPC) * 64;
    const float* feat; const float* wp;
    int HW, lloc, W, wsh; float Wf, Hf;
    if (l0 < 9216)      { feat=f0; wp=wp0; HW=9216; lloc=l0;       W=128; wsh=7; Wf=128.f; Hf=72.f; }
    else if (l0 < 11520){ feat=f1; wp=wp1; HW=2304; lloc=l0-9216;  W=64;  wsh=6; Wf=64.f;  Hf=36.f; }
    else                { feat=f2; wp=wp2; HW=576;  lloc=l0-11520; W=32;  wsh=5; Wf=32.f;  Hf=18.f; }
    const int tid = threadIdx.x;
    const int ty = tid >> 4, tx = tid & 15;
    const int swz = ty << 3;                      // row-group XOR swizzle

    // ---- load A tile: lds layout [c][64] ----
    {
        const float* fb = feat + (size_t)n * CH * HW + lloc;
        #pragma unroll
        for (int rep = 0; rep < 16; ++rep) {
            int idx4 = rep * 1024 + tid * 4;
            int c = idx4 >> 6, l = idx4 & 63;
            float4 v = *reinterpret_cast<const float4*>(fb + (size_t)c * HW + l);
            *reinterpret_cast<float4*>(&lds[c*64 + l]) = v;
        }
    }
    __syncthreads();

    float acc[4][16];
    #pragma unroll
    for (int i=0;i<4;++i)
        #pragma unroll
        for (int j=0;j<16;++j) acc[i][j] = 0.f;

    // ---- stage 1: memory = feat^T @ w_proj ----
    {
        const float* wr = wp + tx*16;
        #pragma unroll 2
        for (int c = 0; c < 256; ++c) {
            const float* wrc = wr + (size_t)c*256;
            float4 b0 = *reinterpret_cast<const float4*>(wrc + 0);
            float4 b1 = *reinterpret_cast<const float4*>(wrc + 4);
            float4 b2 = *reinterpret_cast<const float4*>(wrc + 8);
            float4 b3 = *reinterpret_cast<const float4*>(wrc + 12);
            float bv[16] = {b0.x,b0.y,b0.z,b0.w, b1.x,b1.y,b1.z,b1.w,
                            b2.x,b2.y,b2.z,b2.w, b3.x,b3.y,b3.z,b3.w};
            float4 a4 = *reinterpret_cast<const float4*>(&lds[c*64 + ty*4]);
            float av[4] = {a4.x, a4.y, a4.z, a4.w};
            #pragma unroll
            for (int i=0;i<4;++i)
                #pragma unroll
                for (int j=0;j<16;++j)
                    acc[i][j] = fmaf(av[i], bv[j], acc[i][j]);
        }
    }
    __syncthreads();

    // ---- masked memory -> M-tile in lds (row-major [r][c^swz(r)]) ----
    #pragma unroll
    for (int i=0;i<4;++i) {
        int r  = ty*4 + i;
        int ll = lloc + r;
        int y = ll >> wsh, x = ll & (W-1);
        float px = (x + 0.5f) / Wf;
        float py = (y + 0.5f) / Hf;
        bool valid = (px > 0.01f) && (px < 0.99f) && (py > 0.01f) && (py < 0.99f);
        float m = valid ? 1.f : 0.f;
        #pragma unroll
        for (int j=0;j<16;++j) {
            int col = tx*16 + j;
            lds[r*256 + (col ^ swz)] = acc[i][j] * m;
        }
    }
    __syncthreads();

    // ---- stage 2: enc = masked_mem @ w_enc ----
    #pragma unroll
    for (int i=0;i<4;++i)
        #pragma unroll
        for (int j=0;j<16;++j) acc[i][j] = 0.f;
    {
        const float* wr = w_enc + tx*16;
        #pragma unroll 2
        for (int c = 0; c < 256; ++c) {
            const float* wrc = wr + (size_t)c*256;
            float4 b0 = *reinterpret_cast<const float4*>(wrc + 0);
            float4 b1 = *reinterpret_cast<const float4*>(wrc + 4);
            float4 b2 = *reinterpret_cast<const float4*>(wrc + 8);
            float4 b3 = *reinterpret_cast<const float4*>(wrc + 12);
            float bv[16] = {b0.x,b0.y,b0.z,b0.w, b1.x,b1.y,b1.z,b1.w,
                            b2.x,b2.y,b2.z,b2.w, b3.x,b3.y,b3.z,b3.w};
            int cx = c ^ swz;
            float av[4];
            #pragma unroll
            for (int i=0;i<4;++i) av[i] = lds[(ty*4+i)*256 + cx];
            #pragma unroll
            for (int i=0;i<4;++i)
                #pragma unroll
                for (int j=0;j<16;++j)
                    acc[i][j] = fmaf(av[i], bv[j], acc[i][j]);
        }
    }

    // ---- + b_enc, LayerNorm ----
    float gg[16], hb[16];
    {
        const float* pe = b_enc + tx*16;
        const float* pg = ln_g  + tx*16;
        const float* pb = ln_b  + tx*16;
        #pragma unroll
        for (int j=0;j<16;++j) {
            float e = pe[j];
            #pragma unroll
            for (int i=0;i<4;++i) acc[i][j] += e;
            gg[j] = pg[j]; hb[j] = pb[j];
        }
    }
    #pragma unroll
    for (int i=0;i<4;++i) {
        float s = 0.f;
        #pragma unroll
        for (int j=0;j<16;++j) s += acc[i][j];
        s += __shfl_xor(s,1); s += __shfl_xor(s,2); s += __shfl_xor(s,4); s += __shfl_xor(s,8);
        float mean = s * (1.f/256.f);
        float vs = 0.f;
        #pragma unroll
        for (int j=0;j<16;++j) { float d = acc[i][j]-mean; vs = fmaf(d,d,vs); }
        vs += __shfl_xor(vs,1); vs += __shfl_xor(vs,2); vs += __shfl_xor(vs,4); vs += __shfl_xor(vs,8);
        float rs = 1.f / sqrtf(vs*(1.f/256.f) + 1e-5f);
        #pragma unroll
        for (int j=0;j<16;++j) acc[i][j] = (acc[i][j]-mean)*rs*gg[j] + hb[j];
    }
    __syncthreads();

    // ---- write out_mem + stash in lds for cls ----
    #pragma unroll
    for (int i=0;i<4;++i) {
        int r = ty*4+i;
        float* dst = out_mem + ((size_t)n*LTOT + l0 + r)*CH + tx*16;
        #pragma unroll
        for (int j=0;j<16;j+=4) {
            float4 o = make_float4(acc[i][j],acc[i][j+1],acc[i][j+2],acc[i][j+3]);
            *reinterpret_cast<float4*>(dst + j) = o;
        }
        #pragma unroll
        for (int j=0;j<16;++j) {
            int col = tx*16 + j;
            lds[r*256 + (col ^ swz)] = acc[i][j];
        }
    }
    __syncthreads();

    // ---- stage 3: scores = max over 10 classes of out_mem @ w_cls + b_cls ----
    {
        const int row = tid >> 2, q = tid & 3;
        const int rsw = (row >> 2) << 3;
        float p[10];
        #pragma unroll
        for (int j=0;j<10;++j) p[j]=0.f;
        for (int cc=0; cc<64; ++cc) {
            int c = cc*4 + q;
            float a = lds[row*256 + (c ^ rsw)];
            const float* wc = w_cls + c*10;
            #pragma unroll
            for (int j=0;j<10;++j) p[j] = fmaf(a, wc[j], p[j]);
        }
        #pragma unroll
        for (int j=0;j<10;++j) { p[j] += __shfl_xor(p[j],1); p[j] += __shfl_xor(p[j],2); }
        if (q == 0) {
            float mx = -INFINITY;
            #pragma unroll
            for (int j=0;j<10;++j) mx = fmaxf(mx, p[j] + b_cls[j]);
            scores[(size_t)n*LTOT + l0 + row] = mx;
        }
    }
}

// =====================================================================
// K2/K4: iterative top-k (ties -> lower index, matching lax.top_k)
// =====================================================================
template<int N_ITEMS, int K_SEL>
__global__ __launch_bounds__(256)
void k_topk(const float* __restrict__ vals, int* __restrict__ out_idx, float* __restrict__ out_val)
{
    __shared__ float s[N_ITEMS];
    __shared__ float wv[4]; __shared__ int wi2[4];
    const int b = blockIdx.x, tid = threadIdx.x;
    const float* v = vals + (size_t)b*N_ITEMS;
    for (int i=tid;i<N_ITEMS;i+=256) s[i]=v[i];
    __syncthreads();
    for (int k=0;k<K_SEL;++k) {
        float best=-INFINITY; int bi=0x7fffffff;
        for (int i=tid;i<N_ITEMS;i+=256) {
            float x=s[i];
            if (x>best) {best=x;bi=i;}
        }
        #pragma unroll
        for (int m=1;m<64;m<<=1) {
            float ov=__shfl_xor(best,m); int oi=__shfl_xor(bi,m);
            if (ov>best || (ov==best && oi<bi)) {best=ov;bi=oi;}
        }
        if ((tid&63)==0){ wv[tid>>6]=best; wi2[tid>>6]=bi; }
        __syncthreads();
        if (tid==0){
            for (int q=1;q<4;++q) if (wv[q]>best || (wv[q]==best && wi2[q]<bi)){best=wv[q];bi=wi2[q];}
            out_idx[b*K_SEL + k] = bi;
            out_val[b*K_SEL + k] = best;
            s[bi] = -INFINITY;
        }
        __syncthreads();
    }
}

// =====================================================================
// K3: per selected query (600 blocks): bbox MLP + depth net + center2lidar
// =====================================================================
__global__ __launch_bounds__(256)
void k_query(const float* __restrict__ out_mem, const int* __restrict__ topk_ind,
             const float* __restrict__ intr, const float* __restrict__ ext_inv,
             const float* __restrict__ w_bb1, const float* __restrict__ b_bb1,
             const float* __restrict__ w_bb2, const float* __restrict__ b_bb2,
             const float* __restrict__ w_bb3, const float* __restrict__ b_bb3,
             const float* __restrict__ depth_bins,
             const float* __restrict__ w_d1, const float* __restrict__ b_d1,
             const float* __restrict__ w_d2, const float* __restrict__ b_d2,
             float* __restrict__ dyn_all)
{
    __shared__ float sq[272];
    __shared__ float sh[256];
    __shared__ float sh2[256];
    __shared__ float sbb[2];
    const int nk = blockIdx.x;
    const int n = nk / 100;
    const int tid = threadIdx.x;
    const int l = topk_ind[nk];
    sq[tid] = out_mem[((size_t)n*LTOT + l)*CH + tid];
    if (tid < 16) sq[256+tid] = intr[n*16+tid] * 0.01f;
    __syncthreads();
    // h1
    float s1 = b_bb1[tid];
    for (int c=0;c<256;++c) s1 = fmaf(sq[c], w_bb1[c*256+tid], s1);
    sh[tid] = fmaxf(s1, 0.f);
    __syncthreads();
    // h2
    float s2 = b_bb2[tid];
    for (int c=0;c<256;++c) s2 = fmaf(sh[c], w_bb2[c*256+tid], s2);
    sh2[tid] = fmaxf(s2, 0.f);
    __syncthreads();
    // bbox x,y (components 0,1 only — wh unused downstream)
    {
        int j = tid >> 6, c0 = tid & 63;
        if (j < 2) {
            float p = 0.f;
            #pragma unroll
            for (int t=0;t<4;++t) { int c = c0 + t*64; p = fmaf(sh2[c], w_bb3[c*4+j], p); }
            #pragma unroll
            for (int m=1;m<64;m<<=1) p += __shfl_xor(p, m);
            if (c0 == 0) sbb[j] = p + b_bb3[j] + anchor_comp(l, j);
        }
    }
    // depth hidden layer (reuse sh)
    float t1 = b_d1[tid];
    for (int c=0;c<272;++c) t1 = fmaf(sq[c], w_d1[c*256+tid], t1);
    sh[tid] = fmaxf(t1, 0.f);
    __syncthreads();
    if (tid < 64) {
        float dl = b_d2[tid];
        for (int c=0;c<256;++c) dl = fmaf(sh[c], w_d2[c*64+tid], dl);
        if (isnan(dl)) dl = 0.f;
        if (isinf(dl)) dl = (dl > 0.f) ? 1e4f : -1e4f;
        // softmax over 64 bins (one wave)
        float mx = dl;
        #pragma unroll
        for (int m=1;m<64;m<<=1) mx = fmaxf(mx, __shfl_xor(mx, m));
        float e = expf(dl - mx);
        float sum = e;
        #pragma unroll
        for (int m=1;m<64;m<<=1) sum += __shfl_xor(sum, m);
        float dp = e / sum;
        // center2lidar
        float fx = fmaxf(intr[n*16+0], 1e-6f);
        float fy = fmaxf(intr[n*16+5], 1e-6f);
        float cx = intr[n*16+2], cy = intr[n*16+6];
        float sx = 1.f/(1.f+expf(-sbb[0]));
        float sy = 1.f/(1.f+expf(-sbb[1]));
        float c2dx = sx * 1024.f, c2dy = sy * 576.f;
        float dep = depth_bins[tid];
        float X = (c2dx - cx)/fx*dep;
        float Y = (c2dy - cy)/fy*dep;
        const float* EI = ext_inv + n*16;
        float c0v = EI[0]*X + EI[1]*Y + EI[2]*dep + EI[3];
        float c1v = EI[4]*X + EI[5]*Y + EI[6]*dep + EI[7];
        float c2v = EI[8]*X + EI[9]*Y + EI[10]*dep + EI[11];
        float4 o = make_float4(c0v, c1v, c2v, dp);
        *reinterpret_cast<float4*>(dyn_all + ((size_t)nk*64 + tid)*4) = o;
    }
}

// =====================================================================
// K5: gather final 200 queries
// =====================================================================
__global__ __launch_bounds__(256)
void k_gather(const float* __restrict__ dyn_all, const int* __restrict__ gidx,
              const int* __restrict__ topk_ind, const float* __restrict__ out_mem,
              float* __restrict__ out)
{
    int g = blockIdx.x, tid = threadIdx.x;
    int src = gidx[g];
    out[O_DQ + (size_t)g*256 + tid] = dyn_all[(size_t)src*256 + tid];
    int n = src/100; int l = topk_ind[src];
    out[O_QF + (size_t)g*256 + tid] = out_mem[((size_t)n*LTOT + l)*CH + tid];
}

// =====================================================================
// K6a: MLN gamma/beta per camera
// =====================================================================
__global__ __launch_bounds__(256)
void k_mln(const float* __restrict__ intr, const float* __restrict__ ext,
           const float* __restrict__ w_m1, const float* __restrict__ b_m1,
           const float* __restrict__ w_mg, const float* __restrict__ b_mg,
           const float* __restrict__ w_mb, const float* __restrict__ b_mb,
           float* __restrict__ gamma, float* __restrict__ beta)
{
    __shared__ float hm[256];
    int tid = threadIdx.x;
    for (int n=0;n<CAMS;++n) {
        float m[14];
        m[0] = intr[n*16+0] / 1000.0f;
        m[1] = intr[n*16+5] / 1000.0f;
        #pragma unroll
        for (int j=0;j<12;++j) m[2+j] = ext[n*16+j];
        float h = b_m1[tid];
        #pragma unroll
        for (int k=0;k<14;++k) h = fmaf(m[k], w_m1[k*256+tid], h);
        hm[tid] = fmaxf(h, 0.f);
        __syncthreads();
        float g = b_mg[tid], bt = b_mb[tid];
        for (int c=0;c<256;++c) {
            float hv = hm[c];
            g  = fmaf(hv, w_mg[c*256+tid], g);
            bt = fmaf(hv, w_mb[c*256+tid], bt);
        }
        gamma[n*256+tid] = g;
        beta[n*256+tid]  = bt;
        __syncthreads();
    }
}

// =====================================================================
// K6b: feat_flatten = transpose(feat) * gamma + beta  (64x64 LDS tiles)
// =====================================================================
__global__ __launch_bounds__(256)
void k_flatten(const float* __restrict__ f0, const float* __restrict__ f1,
               const float* __restrict__ gamma, const float* __restrict__ beta,
               float* __restrict__ out)
{
    __shared__ float t[64][65];
    int b = blockIdx.x;
    int lt = b % 180, ct = (b/180) & 3, n = b / 720;
    int l0 = lt*64, c0 = ct*64;
    const float* f; int HW, lb;
    if (l0 < 9216) { f=f0; HW=9216; lb=l0; } else { f=f1; HW=2304; lb=l0-9216; }
    int tid = threadIdx.x;
    int cl = tid >> 4, lw = (tid & 15)*4;
    #pragma unroll
    for (int rep=0;rep<4;++rep) {
        int cc = cl + rep*16;
        float4 v = *reinterpret_cast<const float4*>(f + ((size_t)n*CH + c0+cc)*HW + lb + lw);
        t[cc][lw+0]=v.x; t[cc][lw+1]=v.y; t[cc][lw+2]=v.z; t[cc][lw+3]=v.w;
    }
    __syncthreads();
    int ll = tid >> 4, cw = (tid & 15)*4;
    float4 gv = *reinterpret_cast<const float4*>(gamma + n*256 + c0 + cw);
    float4 bv = *reinterpret_cast<const float4*>(beta  + n*256 + c0 + cw);
    #pragma unroll
    for (int rep=0;rep<4;++rep) {
        int l = ll + rep*16;
        float4 o;
        o.x = fmaf(t[cw+0][l], gv.x, bv.x);
        o.y = fmaf(t[cw+1][l], gv.y, bv.y);
        o.z = fmaf(t[cw+2][l], gv.z, bv.z);
        o.w = fmaf(t[cw+3][l], gv.w, bv.w);
        *reinterpret_cast<float4*>(out + ((size_t)n*LIMG + l0 + l)*CH + c0 + cw) = o;
    }
}

// =====================================================================
// K7: spatial_flatten consts + lidar2img
// =====================================================================
__global__ void k_small(const float* __restrict__ intr, const float* __restrict__ ext,
                        float* __restrict__ out)
{
    int tid = threadIdx.x;
    if (tid < 4) {
        const float sp[4] = {72.f, 128.f, 36.f, 64.f};
        out[O_SP + tid] = sp[tid];
    }
    if (tid < 96) {
        int n = tid >> 4, i = (tid >> 2) & 3, k = tid & 3;
        float s = 0.f;
        #pragma unroll
        for (int j=0;j<4;++j) s = fmaf(intr[n*16 + i*4 + j], ext[n*16 + j*4 + k], s);
        out[O_L2I + tid] = s;
    }
}

// =====================================================================
extern "C" void kernel_launch(void* const* d_in, const int* in_sizes, int n_in,
                              void* d_out, int out_size, void* d_ws, size_t ws_size,
                              hipStream_t stream) {
    const float* f0      = (const float*)d_in[0];
    const float* f1      = (const float*)d_in[1];
    const float* f2      = (const float*)d_in[2];
    const float* intr    = (const float*)d_in[3];
    const float* ext     = (const float*)d_in[4];
    const float* ext_inv = (const float*)d_in[5];
    const float* wp0     = (const float*)d_in[6];
    const float* wp1     = (const float*)d_in[7];
    const float* wp2     = (const float*)d_in[8];
    const float* w_enc   = (const float*)d_in[9];
    const float* b_enc   = (const float*)d_in[10];
    const float* ln_g    = (const float*)d_in[11];
    const float* ln_b    = (const float*)d_in[12];
    const float* w_cls   = (const float*)d_in[13];
    const float* b_cls   = (const float*)d_in[14];
    const float* w_bb1   = (const float*)d_in[15];
    const float* b_bb1   = (const float*)d_in[16];
    const float* w_bb2   = (const float*)d_in[17];
    const float* b_bb2   = (const float*)d_in[18];
    const float* w_bb3   = (const float*)d_in[19];
    const float* b_bb3   = (const float*)d_in[20];
    const float* dbins   = (const float*)d_in[21];
    const float* w_d1    = (const float*)d_in[22];
    const float* b_d1    = (const float*)d_in[23];
    const float* w_d2    = (const float*)d_in[24];
    const float* b_d2    = (const float*)d_in[25];
    const float* w_m1    = (const float*)d_in[26];
    const float* b_m1    = (const float*)d_in[27];
    const float* w_mg    = (const float*)d_in[28];
    const float* b_mg    = (const float*)d_in[29];
    const float* w_mb    = (const float*)d_in[30];
    const float* b_mb    = (const float*)d_in[31];

    float* ws  = (float*)d_ws;
    float* out = (float*)d_out;
    float* om  = ws + WS_OM;
    float* sc  = ws + WS_SC;
    int*   ti  = (int*)(ws + WS_TI);
    float* ts  = ws + WS_TS;
    float* da  = ws + WS_DA;
    int*   gi  = (int*)(ws + WS_GI);
    float* gs  = ws + WS_GS;
    float* ga  = ws + WS_GA;
    float* be  = ws + WS_BE;

    k_encoder<<<CAMS*TPC, 256, 0, stream>>>(f0, f1, f2, wp0, wp1, wp2,
                                            w_enc, b_enc, ln_g, ln_b, w_cls, b_cls,
                                            om, sc);
    k_topk<LTOT, 100><<<CAMS, 256, 0, stream>>>(sc, ti, ts);
    k_query<<<600, 256, 0, stream>>>(om, ti, intr, ext_inv,
                                     w_bb1, b_bb1, w_bb2, b_bb2, w_bb3, b_bb3,
                                     dbins, w_d1, b_d1, w_d2, b_d2, da);
    k_topk<600, 200><<<1, 256, 0, stream>>>(ts, gi, gs);
    k_gather<<<200, 256, 0, stream>>>(da, gi, ti, om, out);
    k_mln<<<1, 256, 0, stream>>>(intr, ext, w_m1, b_m1, w_mg, b_mg, w_mb, b_mb, ga, be);
    k_flatten<<<6*4*180, 256, 0, stream>>>(f0, f1, ga, be, out);
    k_small<<<1, 128, 0, stream>>>(intr, ext, out);
}

// Round 2
// 553.705 us; speedup vs baseline: 2.0406x; 2.0406x over previous
//
#include <hip/hip_runtime.h>
#include <math.h>

#define DEVI __device__ __forceinline__

constexpr int CAMS = 6;
constexpr int CH   = 256;
constexpr int LTOT = 12096;   // 9216 + 2304 + 576
constexpr int TPC  = 378;     // 32-row tiles per camera
constexpr int LIMG = 11520;   // 9216 + 2304

// ---------------- workspace layout (float units) ----------------
constexpr size_t WS_OM = 0;                               // out_mem [6][12096][256]
constexpr size_t WS_SC = WS_OM + (size_t)CAMS*LTOT*CH;    // scores  [6][12096]
constexpr size_t WS_TI = WS_SC + (size_t)CAMS*LTOT;       // topk_ind  600 (int32)
constexpr size_t WS_TS = WS_TI + 768;                     // topk_scores 600
constexpr size_t WS_DA = WS_TS + 768;                     // dyn_all [600][64][4]
constexpr size_t WS_GI = WS_DA + (size_t)600*256;         // gidx 200 (int32)
constexpr size_t WS_GS = WS_GI + 256;                     // (spare)
constexpr size_t WS_GA = WS_GS + 256;                     // gamma [6][256]
constexpr size_t WS_BE = WS_GA + 1536;                    // beta  [6][256]
constexpr size_t WS_AI = WS_BE + 1536;                    // phaseA idx [36][100] int
constexpr size_t WS_AS = WS_AI + 3712;                    // phaseA scores [36][100]

// ---------------- output layout (float units) ----------------
constexpr size_t O_FF  = 0;                               // feat_flatten [6][11520][256]
constexpr size_t O_SP  = (size_t)CAMS*LIMG*CH;            // spatial [2][2]
constexpr size_t O_L2I = O_SP + 4;                        // lidar2img [1][6][4][4]
constexpr size_t O_DQ  = O_L2I + 96;                      // dyn_query [1][200][64][4]
constexpr size_t O_QF  = O_DQ + (size_t)200*64*4;         // qf_out [1][200][256]

DEVI float anchor_comp(int l, int j) {
    int W, wsh, ll; float Wf, Hf;
    if (l < 9216)      { W=128; wsh=7; Wf=128.f; Hf=72.f; ll=l; }
    else if (l < 11520){ W=64;  wsh=6; Wf=64.f;  Hf=36.f; ll=l-9216; }
    else               { W=32;  wsh=5; Wf=32.f;  Hf=18.f; ll=l-11520; }
    int y = ll >> wsh, x = ll & (W-1);
    float px = (x + 0.5f) / Wf;
    float py = (y + 0.5f) / Hf;
    bool valid = (px > 0.01f) && (px < 0.99f) && (py > 0.01f) && (py < 0.99f);
    if (!valid) return INFINITY;
    float p = (j == 0) ? px : py;
    return logf(p / (1.f - p));
}

// =====================================================================
// K1: fused  proj -> mask -> enc -> LayerNorm -> (out_mem, scores)
// 32 tokens/block, 256 threads: thread (ty,tx) owns rows {2ty,2ty+1},
// cols [16tx,16tx+16). Stage-1 result kept in registers; stage-2 A via
// intra-wave shuffles. Weights double-buffered through 32KB LDS.
// =====================================================================
__global__ __launch_bounds__(256, 4)
void k_encoder(const float* __restrict__ f0, const float* __restrict__ f1, const float* __restrict__ f2,
               const float* __restrict__ wp0, const float* __restrict__ wp1, const float* __restrict__ wp2,
               const float* __restrict__ w_enc, const float* __restrict__ b_enc,
               const float* __restrict__ ln_g, const float* __restrict__ ln_b,
               const float* __restrict__ w_cls, const float* __restrict__ b_cls,
               float* __restrict__ out_mem, float* __restrict__ scores)
{
    __shared__ __align__(16) float wbuf[2*4096];   // 2 x [16 c-rows][256], swizzled
    const int bx = blockIdx.x;
    const int n  = bx / TPC;
    const int l0 = (bx % TPC) * 32;
    const float* feat; const float* wp;
    int HW, lloc, W, wsh; float Wf, Hf;
    if (l0 < 9216)      { feat=f0; wp=wp0; HW=9216; lloc=l0;       W=128; wsh=7; Wf=128.f; Hf=72.f; }
    else if (l0 < 11520){ feat=f1; wp=wp1; HW=2304; lloc=l0-9216;  W=64;  wsh=6; Wf=64.f;  Hf=36.f; }
    else                { feat=f2; wp=wp2; HW=576;  lloc=l0-11520; W=32;  wsh=5; Wf=32.f;  Hf=18.f; }
    const int tid = threadIdx.x;
    const int ty = tid >> 4, tx = tid & 15;
    // swizzled column offsets for this thread's 4 float4 slots
    const int sx = (tx & 7) << 2;
    const int off0 = (tx*16 +  0) ^ sx;
    const int off1 = (tx*16 +  4) ^ sx;
    const int off2 = (tx*16 +  8) ^ sx;
    const int off3 = (tx*16 + 12) ^ sx;

    // stage one 16-row weight chunk into LDS (swizzled)
    auto stage_w = [&](const float* __restrict__ wsrc, int chunk, float* __restrict__ dst) {
        const float* src = wsrc + (size_t)(chunk*16 + ty)*256 + tx*16;
        float* d = dst + ty*256;
        #pragma unroll
        for (int q = 0; q < 4; ++q) {
            float4 v = *reinterpret_cast<const float4*>(src + 4*q);
            int col = tx*16 + 4*q;
            *reinterpret_cast<float4*>(d + (col ^ sx)) = v;
        }
    };

    float acc0[16], acc1[16];
    #pragma unroll
    for (int j=0;j<16;++j) { acc0[j]=0.f; acc1[j]=0.f; }

    const float* fb = feat + (size_t)n*CH*HW + lloc + 2*ty;

    stage_w(wp, 0, wbuf);
    __syncthreads();
    int buf = 0;

    // ---- stage 1: memory = feat^T @ w_proj (A direct from global) ----
    for (int k = 0; k < 16; ++k) {
        const float* nsrc = (k < 15) ? wp : w_enc;
        stage_w(nsrc, (k+1) & 15, wbuf + (buf^1)*4096);
        const float* ap = fb + (size_t)(k*16)*HW;
        const float* wb = wbuf + buf*4096;
        #pragma unroll
        for (int cl = 0; cl < 16; ++cl) {
            float2 a = *reinterpret_cast<const float2*>(ap + (size_t)cl*HW);
            const float* wr = wb + cl*256;
            float4 w0 = *reinterpret_cast<const float4*>(wr + off0);
            float4 w1 = *reinterpret_cast<const float4*>(wr + off1);
            float4 w2 = *reinterpret_cast<const float4*>(wr + off2);
            float4 w3 = *reinterpret_cast<const float4*>(wr + off3);
            float wv[16] = {w0.x,w0.y,w0.z,w0.w, w1.x,w1.y,w1.z,w1.w,
                            w2.x,w2.y,w2.z,w2.w, w3.x,w3.y,w3.z,w3.w};
            #pragma unroll
            for (int j=0;j<16;++j) {
                acc0[j] = fmaf(a.x, wv[j], acc0[j]);
                acc1[j] = fmaf(a.y, wv[j], acc1[j]);
            }
        }
        __syncthreads();
        buf ^= 1;
    }

    // ---- mask -> m registers, clear acc ----
    float m0[16], m1[16];
    {
        float mk[2];
        #pragma unroll
        for (int i=0;i<2;++i) {
            int ll = lloc + 2*ty + i;
            int y = ll >> wsh, x = ll & (W-1);
            float px = (x + 0.5f) / Wf;
            float py = (y + 0.5f) / Hf;
            bool valid = (px > 0.01f) && (px < 0.99f) && (py > 0.01f) && (py < 0.99f);
            mk[i] = valid ? 1.f : 0.f;
        }
        #pragma unroll
        for (int j=0;j<16;++j) {
            m0[j] = acc0[j]*mk[0]; m1[j] = acc1[j]*mk[1];
            acc0[j] = 0.f; acc1[j] = 0.f;
        }
    }

    // ---- stage 2: enc = masked_mem @ w_enc (A via intra-wave shuffles) ----
    for (int k = 0; k < 16; ++k) {
        if (k < 15) stage_w(w_enc, k+1, wbuf + (buf^1)*4096);
        const float* wb = wbuf + buf*4096;
        const int src = (tid & 48) | k;
        #pragma unroll
        for (int cl = 0; cl < 16; ++cl) {
            float a0 = __shfl(m0[cl], src);
            float a1 = __shfl(m1[cl], src);
            const float* wr = wb + cl*256;
            float4 w0 = *reinterpret_cast<const float4*>(wr + off0);
            float4 w1 = *reinterpret_cast<const float4*>(wr + off1);
            float4 w2 = *reinterpret_cast<const float4*>(wr + off2);
            float4 w3 = *reinterpret_cast<const float4*>(wr + off3);
            float wv[16] = {w0.x,w0.y,w0.z,w0.w, w1.x,w1.y,w1.z,w1.w,
                            w2.x,w2.y,w2.z,w2.w, w3.x,w3.y,w3.z,w3.w};
            #pragma unroll
            for (int j=0;j<16;++j) {
                acc0[j] = fmaf(a0, wv[j], acc0[j]);
                acc1[j] = fmaf(a1, wv[j], acc1[j]);
            }
        }
        __syncthreads();
        buf ^= 1;
    }

    // ---- + b_enc, LayerNorm (rows reduce across 16 tx lanes) ----
    {
        const float* pe = b_enc + tx*16;
        const float* pg = ln_g  + tx*16;
        const float* pb = ln_b  + tx*16;
        float gg[16], hb[16];
        #pragma unroll
        for (int j=0;j<16;++j) {
            float e = pe[j];
            acc0[j] += e; acc1[j] += e;
            gg[j] = pg[j]; hb[j] = pb[j];
        }
        float s0=0.f, s1=0.f;
        #pragma unroll
        for (int j=0;j<16;++j) { s0 += acc0[j]; s1 += acc1[j]; }
        s0 += __shfl_xor(s0,1); s0 += __shfl_xor(s0,2); s0 += __shfl_xor(s0,4); s0 += __shfl_xor(s0,8);
        s1 += __shfl_xor(s1,1); s1 += __shfl_xor(s1,2); s1 += __shfl_xor(s1,4); s1 += __shfl_xor(s1,8);
        float mean0 = s0*(1.f/256.f), mean1 = s1*(1.f/256.f);
        float v0=0.f, v1=0.f;
        #pragma unroll
        for (int j=0;j<16;++j) {
            float d0 = acc0[j]-mean0; v0 = fmaf(d0,d0,v0);
            float d1 = acc1[j]-mean1; v1 = fmaf(d1,d1,v1);
        }
        v0 += __shfl_xor(v0,1); v0 += __shfl_xor(v0,2); v0 += __shfl_xor(v0,4); v0 += __shfl_xor(v0,8);
        v1 += __shfl_xor(v1,1); v1 += __shfl_xor(v1,2); v1 += __shfl_xor(v1,4); v1 += __shfl_xor(v1,8);
        float r0 = 1.f/sqrtf(v0*(1.f/256.f) + 1e-5f);
        float r1 = 1.f/sqrtf(v1*(1.f/256.f) + 1e-5f);
        #pragma unroll
        for (int j=0;j<16;++j) {
            acc0[j] = (acc0[j]-mean0)*r0*gg[j] + hb[j];
            acc1[j] = (acc1[j]-mean1)*r1*gg[j] + hb[j];
        }
    }

    // ---- write out_mem ----
    {
        float* d0 = out_mem + ((size_t)n*LTOT + l0 + 2*ty  )*CH + tx*16;
        float* d1 = out_mem + ((size_t)n*LTOT + l0 + 2*ty+1)*CH + tx*16;
        #pragma unroll
        for (int j=0;j<16;j+=4) {
            *reinterpret_cast<float4*>(d0+j) = make_float4(acc0[j],acc0[j+1],acc0[j+2],acc0[j+3]);
            *reinterpret_cast<float4*>(d1+j) = make_float4(acc1[j],acc1[j+1],acc1[j+2],acc1[j+3]);
        }
    }

    // ---- stage 3: scores (partial per-tx sums, reduce across tx) ----
    {
        float p0[10], p1[10];
        #pragma unroll
        for (int c=0;c<10;++c) { p0[c]=0.f; p1[c]=0.f; }
        const float* wc = w_cls + (size_t)tx*160;
        #pragma unroll
        for (int j=0;j<16;++j) {
            float e0 = acc0[j], e1 = acc1[j];
            #pragma unroll
            for (int c=0;c<10;c+=2) {
                float2 wv = *reinterpret_cast<const float2*>(wc + j*10 + c);
                p0[c]   = fmaf(e0, wv.x, p0[c]);   p0[c+1] = fmaf(e0, wv.y, p0[c+1]);
                p1[c]   = fmaf(e1, wv.x, p1[c]);   p1[c+1] = fmaf(e1, wv.y, p1[c+1]);
            }
        }
        #pragma unroll
        for (int c=0;c<10;++c) {
            p0[c] += __shfl_xor(p0[c],1); p0[c] += __shfl_xor(p0[c],2);
            p0[c] += __shfl_xor(p0[c],4); p0[c] += __shfl_xor(p0[c],8);
            p1[c] += __shfl_xor(p1[c],1); p1[c] += __shfl_xor(p1[c],2);
            p1[c] += __shfl_xor(p1[c],4); p1[c] += __shfl_xor(p1[c],8);
        }
        if (tx == 0) {
            float mx0 = -INFINITY, mx1 = -INFINITY;
            #pragma unroll
            for (int c=0;c<10;++c) {
                float bc = b_cls[c];
                mx0 = fmaxf(mx0, p0[c] + bc);
                mx1 = fmaxf(mx1, p1[c] + bc);
            }
            scores[(size_t)n*LTOT + l0 + 2*ty    ] = mx0;
            scores[(size_t)n*LTOT + l0 + 2*ty + 1] = mx1;
        }
    }
}

// =====================================================================
// sort-based top-k (exact lax.top_k semantics: desc by score, ties ->
// lower index). Key = (monotone-mapped score << 32) | ~idx, sorted desc.
// =====================================================================
typedef unsigned long long u64;

DEVI u64 pack_key(float s, unsigned idx) {
    unsigned u = __float_as_uint(s);
    u = (u & 0x80000000u) ? ~u : (u | 0x80000000u);
    return ((u64)u << 32) | (unsigned)(~idx);
}
DEVI float key_score(u64 k) {
    unsigned u = (unsigned)(k >> 32);
    u = (u & 0x80000000u) ? (u ^ 0x80000000u) : ~u;
    return __uint_as_float(u);
}
DEVI int key_idx(u64 k) { return (int)(~(unsigned)k); }

template<int N>
DEVI void bitonic_desc(u64* s, int tid) {
    for (int size = 2; size <= N; size <<= 1) {
        for (int stride = size >> 1; stride > 0; stride >>= 1) {
            __syncthreads();
            #pragma unroll 2
            for (int t = tid; t < N/2; t += 256) {
                int lo = ((t & ~(stride-1)) << 1) | (t & (stride-1));
                int hi = lo + stride;
                bool desc = ((lo & size) == 0);
                u64 a = s[lo], b = s[hi];
                if ((a < b) == desc) { s[lo] = b; s[hi] = a; }
            }
        }
    }
    __syncthreads();
}

// Phase A: 36 blocks = (cam, seg). Sort each 2016-item segment, keep top-100.
__global__ __launch_bounds__(256)
void k_sortA(const float* __restrict__ scores, int* __restrict__ outi, float* __restrict__ outs)
{
    __shared__ u64 s[2048];
    const int b = blockIdx.x, tid = threadIdx.x;
    const int cam = b / 6, seg = b % 6;
    const float* v = scores + (size_t)cam*LTOT + seg*2016;
    for (int i = tid; i < 2048; i += 256)
        s[i] = (i < 2016) ? pack_key(v[i], seg*2016 + i) : 0ull;
    bitonic_desc<2048>(s, tid);
    if (tid < 100) {
        u64 k = s[tid];
        outi[b*100 + tid] = key_idx(k);
        outs[b*100 + tid] = key_score(k);
    }
}

// Phase B: 6 blocks (per cam). Merge 600 -> top-100 (sorted).
__global__ __launch_bounds__(256)
void k_sortB(const int* __restrict__ ai, const float* __restrict__ as,
             int* __restrict__ ti, float* __restrict__ ts)
{
    __shared__ u64 s[1024];
    const int cam = blockIdx.x, tid = threadIdx.x;
    for (int i = tid; i < 1024; i += 256)
        s[i] = (i < 600) ? pack_key(as[cam*600 + i], (unsigned)ai[cam*600 + i]) : 0ull;
    bitonic_desc<1024>(s, tid);
    if (tid < 100) {
        u64 k = s[tid];
        ti[cam*100 + tid] = key_idx(k);
        ts[cam*100 + tid] = key_score(k);
    }
}

// Phase C: 1 block. Global top-200 over the 600 topk_scores (index = nk pos).
__global__ __launch_bounds__(256)
void k_sortC(const float* __restrict__ ts, int* __restrict__ gi)
{
    __shared__ u64 s[1024];
    const int tid = threadIdx.x;
    for (int i = tid; i < 1024; i += 256)
        s[i] = (i < 600) ? pack_key(ts[i], (unsigned)i) : 0ull;
    bitonic_desc<1024>(s, tid);
    if (tid < 200) gi[tid] = key_idx(s[tid]);
}

// =====================================================================
// K3: per selected query (600 blocks): bbox MLP + depth net + center2lidar
// =====================================================================
__global__ __launch_bounds__(256)
void k_query(const float* __restrict__ out_mem, const int* __restrict__ topk_ind,
             const float* __restrict__ intr, const float* __restrict__ ext_inv,
             const float* __restrict__ w_bb1, const float* __restrict__ b_bb1,
             const float* __restrict__ w_bb2, const float* __restrict__ b_bb2,
             const float* __restrict__ w_bb3, const float* __restrict__ b_bb3,
             const float* __restrict__ depth_bins,
             const float* __restrict__ w_d1, const float* __restrict__ b_d1,
             const float* __restrict__ w_d2, const float* __restrict__ b_d2,
             float* __restrict__ dyn_all)
{
    __shared__ float sq[272];
    __shared__ float sh[256];
    __shared__ float sh2[256];
    __shared__ float sbb[2];
    const int nk = blockIdx.x;
    const int n = nk / 100;
    const int tid = threadIdx.x;
    const int l = topk_ind[nk];
    sq[tid] = out_mem[((size_t)n*LTOT + l)*CH + tid];
    if (tid < 16) sq[256+tid] = intr[n*16+tid] * 0.01f;
    __syncthreads();
    float s1 = b_bb1[tid];
    for (int c=0;c<256;++c) s1 = fmaf(sq[c], w_bb1[c*256+tid], s1);
    sh[tid] = fmaxf(s1, 0.f);
    __syncthreads();
    float s2 = b_bb2[tid];
    for (int c=0;c<256;++c) s2 = fmaf(sh[c], w_bb2[c*256+tid], s2);
    sh2[tid] = fmaxf(s2, 0.f);
    __syncthreads();
    {
        int j = tid >> 6, c0 = tid & 63;
        if (j < 2) {
            float p = 0.f;
            #pragma unroll
            for (int t=0;t<4;++t) { int c = c0 + t*64; p = fmaf(sh2[c], w_bb3[c*4+j], p); }
            #pragma unroll
            for (int m=1;m<64;m<<=1) p += __shfl_xor(p, m);
            if (c0 == 0) sbb[j] = p + b_bb3[j] + anchor_comp(l, j);
        }
    }
    float t1 = b_d1[tid];
    for (int c=0;c<272;++c) t1 = fmaf(sq[c], w_d1[c*256+tid], t1);
    sh[tid] = fmaxf(t1, 0.f);
    __syncthreads();
    if (tid < 64) {
        float dl = b_d2[tid];
        for (int c=0;c<256;++c) dl = fmaf(sh[c], w_d2[c*64+tid], dl);
        if (isnan(dl)) dl = 0.f;
        if (isinf(dl)) dl = (dl > 0.f) ? 1e4f : -1e4f;
        float mx = dl;
        #pragma unroll
        for (int m=1;m<64;m<<=1) mx = fmaxf(mx, __shfl_xor(mx, m));
        float e = expf(dl - mx);
        float sum = e;
        #pragma unroll
        for (int m=1;m<64;m<<=1) sum += __shfl_xor(sum, m);
        float dp = e / sum;
        float fx = fmaxf(intr[n*16+0], 1e-6f);
        float fy = fmaxf(intr[n*16+5], 1e-6f);
        float cx = intr[n*16+2], cy = intr[n*16+6];
        float sx = 1.f/(1.f+expf(-sbb[0]));
        float sy = 1.f/(1.f+expf(-sbb[1]));
        float c2dx = sx * 1024.f, c2dy = sy * 576.f;
        float dep = depth_bins[tid];
        float X = (c2dx - cx)/fx*dep;
        float Y = (c2dy - cy)/fy*dep;
        const float* EI = ext_inv + n*16;
        float c0v = EI[0]*X + EI[1]*Y + EI[2]*dep + EI[3];
        float c1v = EI[4]*X + EI[5]*Y + EI[6]*dep + EI[7];
        float c2v = EI[8]*X + EI[9]*Y + EI[10]*dep + EI[11];
        float4 o = make_float4(c0v, c1v, c2v, dp);
        *reinterpret_cast<float4*>(dyn_all + ((size_t)nk*64 + tid)*4) = o;
    }
}

// =====================================================================
// K5: gather final 200 queries
// =====================================================================
__global__ __launch_bounds__(256)
void k_gather(const float* __restrict__ dyn_all, const int* __restrict__ gidx,
              const int* __restrict__ topk_ind, const float* __restrict__ out_mem,
              float* __restrict__ out)
{
    int g = blockIdx.x, tid = threadIdx.x;
    int src = gidx[g];
    out[O_DQ + (size_t)g*256 + tid] = dyn_all[(size_t)src*256 + tid];
    int n = src/100; int l = topk_ind[src];
    out[O_QF + (size_t)g*256 + tid] = out_mem[((size_t)n*LTOT + l)*CH + tid];
}

// =====================================================================
// K6a: MLN gamma/beta per camera
// =====================================================================
__global__ __launch_bounds__(256)
void k_mln(const float* __restrict__ intr, const float* __restrict__ ext,
           const float* __restrict__ w_m1, const float* __restrict__ b_m1,
           const float* __restrict__ w_mg, const float* __restrict__ b_mg,
           const float* __restrict__ w_mb, const float* __restrict__ b_mb,
           float* __restrict__ gamma, float* __restrict__ beta)
{
    __shared__ float hm[256];
    int tid = threadIdx.x;
    for (int n=0;n<CAMS;++n) {
        float m[14];
        m[0] = intr[n*16+0] / 1000.0f;
        m[1] = intr[n*16+5] / 1000.0f;
        #pragma unroll
        for (int j=0;j<12;++j) m[2+j] = ext[n*16+j];
        float h = b_m1[tid];
        #pragma unroll
        for (int k=0;k<14;++k) h = fmaf(m[k], w_m1[k*256+tid], h);
        hm[tid] = fmaxf(h, 0.f);
        __syncthreads();
        float g = b_mg[tid], bt = b_mb[tid];
        for (int c=0;c<256;++c) {
            float hv = hm[c];
            g  = fmaf(hv, w_mg[c*256+tid], g);
            bt = fmaf(hv, w_mb[c*256+tid], bt);
        }
        gamma[n*256+tid] = g;
        beta[n*256+tid]  = bt;
        __syncthreads();
    }
}

// =====================================================================
// K6b: feat_flatten = transpose(feat) * gamma + beta  (64x64 LDS tiles)
// =====================================================================
__global__ __launch_bounds__(256)
void k_flatten(const float* __restrict__ f0, const float* __restrict__ f1,
               const float* __restrict__ gamma, const float* __restrict__ beta,
               float* __restrict__ out)
{
    __shared__ float t[64][65];
    int b = blockIdx.x;
    int lt = b % 180, ct = (b/180) & 3, n = b / 720;
    int l0 = lt*64, c0 = ct*64;
    const float* f; int HW, lb;
    if (l0 < 9216) { f=f0; HW=9216; lb=l0; } else { f=f1; HW=2304; lb=l0-9216; }
    int tid = threadIdx.x;
    int cl = tid >> 4, lw = (tid & 15)*4;
    #pragma unroll
    for (int rep=0;rep<4;++rep) {
        int cc = cl + rep*16;
        float4 v = *reinterpret_cast<const float4*>(f + ((size_t)n*CH + c0+cc)*HW + lb + lw);
        t[cc][lw+0]=v.x; t[cc][lw+1]=v.y; t[cc][lw+2]=v.z; t[cc][lw+3]=v.w;
    }
    __syncthreads();
    int ll = tid >> 4, cw = (tid & 15)*4;
    float4 gv = *reinterpret_cast<const float4*>(gamma + n*256 + c0 + cw);
    float4 bv = *reinterpret_cast<const float4*>(beta  + n*256 + c0 + cw);
    #pragma unroll
    for (int rep=0;rep<4;++rep) {
        int l = ll + rep*16;
        float4 o;
        o.x = fmaf(t[cw+0][l], gv.x, bv.x);
        o.y = fmaf(t[cw+1][l], gv.y, bv.y);
        o.z = fmaf(t[cw+2][l], gv.z, bv.z);
        o.w = fmaf(t[cw+3][l], gv.w, bv.w);
        *reinterpret_cast<float4*>(out + ((size_t)n*LIMG + l0 + l)*CH + c0 + cw) = o;
    }
}

// =====================================================================
// K7: spatial_flatten consts + lidar2img
// =====================================================================
__global__ void k_small(const float* __restrict__ intr, const float* __restrict__ ext,
                        float* __restrict__ out)
{
    int tid = threadIdx.x;
    if (tid < 4) {
        const float sp[4] = {72.f, 128.f, 36.f, 64.f};
        out[O_SP + tid] = sp[tid];
    }
    if (tid < 96) {
        int n = tid >> 4, i = (tid >> 2) & 3, k = tid & 3;
        float s = 0.f;
        #pragma unroll
        for (int j=0;j<4;++j) s = fmaf(intr[n*16 + i*4 + j], ext[n*16 + j*4 + k], s);
        out[O_L2I + tid] = s;
    }
}

// =====================================================================
extern "C" void kernel_launch(void* const* d_in, const int* in_sizes, int n_in,
                              void* d_out, int out_size, void* d_ws, size_t ws_size,
                              hipStream_t stream) {
    const float* f0      = (const float*)d_in[0];
    const float* f1      = (const float*)d_in[1];
    const float* f2      = (const float*)d_in[2];
    const float* intr    = (const float*)d_in[3];
    const float* ext     = (const float*)d_in[4];
    const float* ext_inv = (const float*)d_in[5];
    const float* wp0     = (const float*)d_in[6];
    const float* wp1     = (const float*)d_in[7];
    const float* wp2     = (const float*)d_in[8];
    const float* w_enc   = (const float*)d_in[9];
    const float* b_enc   = (const float*)d_in[10];
    const float* ln_g    = (const float*)d_in[11];
    const float* ln_b    = (const float*)d_in[12];
    const float* w_cls   = (const float*)d_in[13];
    const float* b_cls   = (const float*)d_in[14];
    const float* w_bb1   = (const float*)d_in[15];
    const float* b_bb1   = (const float*)d_in[16];
    const float* w_bb2   = (const float*)d_in[17];
    const float* b_bb2   = (const float*)d_in[18];
    const float* w_bb3   = (const float*)d_in[19];
    const float* b_bb3   = (const float*)d_in[20];
    const float* dbins   = (const float*)d_in[21];
    const float* w_d1    = (const float*)d_in[22];
    const float* b_d1    = (const float*)d_in[23];
    const float* w_d2    = (const float*)d_in[24];
    const float* b_d2    = (const float*)d_in[25];
    const float* w_m1    = (const float*)d_in[26];
    const float* b_m1    = (const float*)d_in[27];
    const float* w_mg    = (const float*)d_in[28];
    const float* b_mg    = (const float*)d_in[29];
    const float* w_mb    = (const float*)d_in[30];
    const float* b_mb    = (const float*)d_in[31];

    float* ws  = (float*)d_ws;
    float* out = (float*)d_out;
    float* om  = ws + WS_OM;
    float* sc  = ws + WS_SC;
    int*   ti  = (int*)(ws + WS_TI);
    float* ts  = ws + WS_TS;
    float* da  = ws + WS_DA;
    int*   gi  = (int*)(ws + WS_GI);
    float* ga  = ws + WS_GA;
    float* be  = ws + WS_BE;
    int*   ai  = (int*)(ws + WS_AI);
    float* as  = ws + WS_AS;

    k_encoder<<<CAMS*TPC, 256, 0, stream>>>(f0, f1, f2, wp0, wp1, wp2,
                                            w_enc, b_enc, ln_g, ln_b, w_cls, b_cls,
                                            om, sc);
    k_sortA<<<36, 256, 0, stream>>>(sc, ai, as);
    k_sortB<<<6, 256, 0, stream>>>(ai, as, ti, ts);
    k_query<<<600, 256, 0, stream>>>(om, ti, intr, ext_inv,
                                     w_bb1, b_bb1, w_bb2, b_bb2, w_bb3, b_bb3,
                                     dbins, w_d1, b_d1, w_d2, b_d2, da);
    k_sortC<<<1, 256, 0, stream>>>(ts, gi);
    k_gather<<<200, 256, 0, stream>>>(da, gi, ti, om, out);
    k_mln<<<1, 256, 0, stream>>>(intr, ext, w_m1, b_m1, w_mg, b_mg, w_mb, b_mb, ga, be);
    k_flatten<<<6*4*180, 256, 0, stream>>>(f0, f1, ga, be, out);
    k_small<<<1, 128, 0, stream>>>(intr, ext, out);
}